// Round 14
// baseline (586.148 us; speedup 1.0000x reference)
//
#include <hip/hip_runtime.h>
#include <hip/hip_bf16.h>

#define D 128
#define TILE 2048
// LDS row pitch 136 u16 = 272B = 17x16B: 16B-aligned rows (REQUIRED for b128
// ops -- 132 broke alignment on odd rows and cost +73% despite fewer counted
// bank conflicts, measured r9).

typedef __bf16 bf16x8 __attribute__((ext_vector_type(8)));
typedef float f32x4 __attribute__((ext_vector_type(4)));
typedef unsigned short u16x8 __attribute__((ext_vector_type(8)));

// fast tanh: 1 - 2/(e^{2|x|}+1), sign-restored. v_exp + v_rcp, branch-free,
// saturates to +-1 for large |x|. ~1e-6 rel err.
__device__ __forceinline__ float tanh_fast(float x) {
    float e = __expf(2.0f * fabsf(x));
    float t = 1.0f - 2.0f * __builtin_amdgcn_rcpf(e + 1.0f);
    return copysignf(t, x);
}

__device__ __forceinline__ float bf2f(unsigned short u) {
    return __uint_as_float((unsigned int)u << 16);
}

__device__ __forceinline__ unsigned short f2bf_u16(float x) {
    __hip_bfloat16 t = __float2bfloat16(x);
    return *(unsigned short*)&t;
}

// ds_swizzle BitMode xor-butterfly within 16-lane groups (xor 1,2,4,8).
#define SWZ_F(x, imm) __int_as_float(__builtin_amdgcn_ds_swizzle(__float_as_int(x), imm))

// ---- dtype detection: are float inputs f32 or bf16 on device? flag=1 => f32.
__global__ __launch_bounds__(256) void detect_kernel(const unsigned short* __restrict__ x,
                                                     int* __restrict__ flag) {
    int t = threadIdx.x;
    int cnt = 0;
    for (int i = t; i < 4096; i += 256) {
        unsigned e = (x[i] >> 7) & 0xFFu;
        if (e == 0xFFu || e >= 0x90u || (e >= 1u && e <= 0x6Eu)) cnt++;
    }
    __shared__ int sh[256];
    sh[t] = cnt;
    __syncthreads();
    for (int off = 128; off; off >>= 1) {
        if (t < off) sh[t] += sh[t + off];
        __syncthreads();
    }
    if (t == 0) flag[0] = (sh[0] > 800) ? 1 : 0;
}

struct ConvBatch {
    const void* src[14];
    __hip_bfloat16* dst[14];
    int n[14];
};

// grid = (32, 14): blockIdx.y picks the array, 4 elems/thread vectorized.
__global__ __launch_bounds__(256) void conv_weights_kernel(ConvBatch cb,
                                                           const int* __restrict__ flag) {
    int a = blockIdx.y;
    const void* s = cb.src[a];
    unsigned short* d = (unsigned short*)cb.dst[a];
    int n = cb.n[a];
    int f = flag[0];
    int i = (blockIdx.x * 256 + threadIdx.x) * 4;
    if (i >= n) return;
    if (i + 4 <= n) {
        ushort4 o;
        if (f) {
            float4 v = *(const float4*)((const float*)s + i);
            o.x = f2bf_u16(v.x); o.y = f2bf_u16(v.y);
            o.z = f2bf_u16(v.z); o.w = f2bf_u16(v.w);
        } else {
            o = *(const ushort4*)((const unsigned short*)s + i);
        }
        *(ushort4*)(d + i) = o;
    } else {
        for (int j = i; j < n; j++)
            d[j] = f ? f2bf_u16(((const float*)s)[j])
                     : ((const unsigned short*)s)[j];
    }
}

// 4 elems/thread vectorized; n is a multiple of 4 (N*D).
__global__ __launch_bounds__(256) void conv_x_kernel(const void* __restrict__ src,
                                                     __hip_bfloat16* __restrict__ dst,
                                                     int n, const int* __restrict__ flag) {
    int i = (blockIdx.x * 256 + threadIdx.x) * 4;
    if (i >= n) return;
    int f = flag[0];
    ushort4 o;
    if (f) {
        float4 v = *(const float4*)((const float*)src + i);
        o.x = f2bf_u16(v.x); o.y = f2bf_u16(v.y);
        o.z = f2bf_u16(v.z); o.w = f2bf_u16(v.w);
    } else {
        o = *(const ushort4*)((const unsigned short*)src + i);
    }
    *(ushort4*)((unsigned short*)dst + i) = o;
}

// ---- weight transpose: 7 independent 128x128 blocks -> Wt[c][k] = W[k][c] (bf16)
struct TransBatch {
    const void* base[7];
    int off[7];
    unsigned short* dst[7];
};

// grid = (16, 7): blockIdx.y picks the matrix; 4 consecutive elems/thread
// (same source row), vectorized source read, 4 strided u16 stores.
__global__ __launch_bounds__(256) void trans_kernel(TransBatch tb,
                                                    const int* __restrict__ flag) {
    int a = blockIdx.y;
    int f = flag[0];
    const float* sf = (const float*)tb.base[a] + tb.off[a];
    const unsigned short* sb = (const unsigned short*)tb.base[a] + tb.off[a];
    unsigned short* d = tb.dst[a];
    int idx = (blockIdx.x * 256 + threadIdx.x) * 4;  // < 128*128
    int k = idx >> 7, c = idx & 127;
    unsigned short v[4];
    if (f) {
        float4 x = *(const float4*)(sf + idx);
        v[0] = f2bf_u16(x.x); v[1] = f2bf_u16(x.y);
        v[2] = f2bf_u16(x.z); v[3] = f2bf_u16(x.w);
    } else {
        ushort4 x = *(const ushort4*)(sb + idx);
        v[0] = x.x; v[1] = x.y; v[2] = x.z; v[3] = x.w;
    }
#pragma unroll
    for (int j = 0; j < 4; j++) d[(c + j) * 128 + k] = v[j];
}

__global__ __launch_bounds__(256) void zero_kernel(int* p, int n) {
    int i = blockIdx.x * 256 + threadIdx.x;
    if (i < n) p[i] = 0;
}

// ---- fused degree count for 4 key arrays; grid = (maxE/256, 4).
__global__ __launch_bounds__(256) void count4_kernel(const int* __restrict__ k0,
                                                     const int* __restrict__ k1,
                                                     const int* __restrict__ k2,
                                                     const int* __restrict__ k3,
                                                     int E0, int E1, int E2, int E3,
                                                     int* __restrict__ deg, int N) {
    int y = blockIdx.y;
    const int* k = (y == 0) ? k0 : (y == 1) ? k1 : (y == 2) ? k2 : k3;
    int E = (y == 0) ? E0 : (y == 1) ? E1 : (y == 2) ? E2 : E3;
    int i = blockIdx.x * 256 + threadIdx.x;
    if (i < E) atomicAdd(&deg[y * N + k[i]], 1);
}

// ---- hierarchical scan, phase 1: per-tile sums. grid = 4 * ntpa blocks.
__global__ __launch_bounds__(256) void scan_partial_kernel(const int* __restrict__ deg,
                                                           int* __restrict__ tsum,
                                                           int N, int ntpa) {
    int a = blockIdx.x / ntpa, t = blockIdx.x % ntpa;
    const int* d = deg + (size_t)a * N + (size_t)t * TILE;
    int lim = N - t * TILE; if (lim > TILE) lim = TILE;
    int base = threadIdx.x * 8;
    int s = 0;
#pragma unroll
    for (int j = 0; j < 8; j++) {
        int i = base + j;
        if (i < lim) s += d[i];
    }
    __shared__ int sh[256];
    sh[threadIdx.x] = s;
    __syncthreads();
    for (int off = 128; off; off >>= 1) {
        if (threadIdx.x < off) sh[threadIdx.x] += sh[threadIdx.x + off];
        __syncthreads();
    }
    if (threadIdx.x == 0) tsum[blockIdx.x] = sh[0];
}

// ---- phase 2: exclusive scan of tile sums per array (ntpa <= 256); one block.
__global__ __launch_bounds__(256) void scan_tiles_kernel(const int* __restrict__ tsum,
                                                         int* __restrict__ toff,
                                                         int* __restrict__ indptr,
                                                         int N, int ntpa) {
    __shared__ int tmp[256];
    int t = threadIdx.x;
    for (int a = 0; a < 4; a++) {
        int v = (t < ntpa) ? tsum[a * ntpa + t] : 0;
        tmp[t] = v;
        __syncthreads();
        for (int off = 1; off < 256; off <<= 1) {
            int u = (t >= off) ? tmp[t - off] : 0;
            __syncthreads();
            tmp[t] += u;
            __syncthreads();
        }
        if (t < ntpa) toff[a * ntpa + t] = tmp[t] - v;  // exclusive
        if (t == ntpa - 1) indptr[(size_t)a * (N + 1) + N] = tmp[t];
        __syncthreads();
    }
}

// ---- phase 3: intra-tile scan + tile offset; writes indptr and cursor.
__global__ __launch_bounds__(256) void scan_final_kernel(int* __restrict__ degcur,
                                                         const int* __restrict__ toff,
                                                         int* __restrict__ indptr,
                                                         int N, int ntpa) {
    int a = blockIdx.x / ntpa, t = blockIdx.x % ntpa;
    int* d = degcur + (size_t)a * N + (size_t)t * TILE;
    int* ip = indptr + (size_t)a * (N + 1) + (size_t)t * TILE;
    int lim = N - t * TILE; if (lim > TILE) lim = TILE;
    int base = threadIdx.x * 8;
    int v[8];
    int s = 0;
#pragma unroll
    for (int j = 0; j < 8; j++) {
        int i = base + j;
        v[j] = (i < lim) ? d[i] : 0;
        s += v[j];
    }
    __shared__ int tmp[256];
    tmp[threadIdx.x] = s;
    __syncthreads();
    for (int off = 1; off < 256; off <<= 1) {
        int u = (threadIdx.x >= off) ? tmp[threadIdx.x - off] : 0;
        __syncthreads();
        tmp[threadIdx.x] += u;
        __syncthreads();
    }
    int run = toff[blockIdx.x] + tmp[threadIdx.x] - s;
#pragma unroll
    for (int j = 0; j < 8; j++) {
        int i = base + j;
        if (i < lim) { ip[i] = run; d[i] = run; run += v[j]; }
    }
}

// ---- fused scatter for all 4 CSR payloads; grid = (maxE/256, 4).
// Payload is 4B only (key is implied by the segment in per-node consumers):
// one dirty line per edge, arrays 2MB each (L2-resident).
__global__ __launch_bounds__(256) void scatter4_kernel(
    const int* __restrict__ k0, const int* __restrict__ p0,
    const int* __restrict__ k1, const int* __restrict__ p1,
    const int* __restrict__ k2, const int* __restrict__ p2,
    const int* __restrict__ k3, const int* __restrict__ p3,
    int E0, int E1, int E2, int E3,
    int* __restrict__ cursor, int N,
    int* __restrict__ o0, int* __restrict__ o1,
    int* __restrict__ o2, int* __restrict__ o3) {
    int y = blockIdx.y;
    const int* keys = (y == 0) ? k0 : (y == 1) ? k1 : (y == 2) ? k2 : k3;
    const int* pays = (y == 0) ? p0 : (y == 1) ? p1 : (y == 2) ? p2 : p3;
    int E = (y == 0) ? E0 : (y == 1) ? E1 : (y == 2) ? E2 : E3;
    int* cur = cursor + (size_t)y * N;
    int* out = (y == 0) ? o0 : (y == 1) ? o1 : (y == 2) ? o2 : o3;
    int i = blockIdx.x * 256 + threadIdx.x;
    if (i < E) {
        int p = atomicAdd(&cur[keys[i]], 1);
        out[p] = pays[i];
    }
}

// ---- MFMA GEMM: B staged in LDS per 128-col half; A fragments direct from
// global per wave (dense guarded 64B segments) -- no A stage, no A barrier.
// (Measured best gemm2 variant, r6.)
__global__ __launch_bounds__(256) void gemm2_mfma_kernel(
    const __hip_bfloat16* __restrict__ X,
    const unsigned short* __restrict__ Wt,      // 256 x 128, Wt[c][k]
    const __hip_bfloat16* __restrict__ bias,    // 128 (part1 only)
    __hip_bfloat16* __restrict__ part0,
    __hip_bfloat16* __restrict__ part1, int N) {
    __shared__ __align__(16) unsigned short Bs[128 * 136];
    int n0 = blockIdx.x * 64;
    int w = threadIdx.x >> 6, lane = threadIdx.x & 63;
    int n15 = lane & 15, quad = lane >> 4;
    int arow = n0 + w * 16 + n15;
    const unsigned short* ap = (const unsigned short*)X + (size_t)arow * D + quad * 8;
    bf16x8 af[4];
#pragma unroll
    for (int t = 0; t < 4; t++) {
        bf16x8 v = {};
        if (arow < N) v = *(const bf16x8*)(ap + t * 32);
        af[t] = v;
    }
    for (int half = 0; half < 2; half++) {
        if (half) __syncthreads();  // all reads of Bs done before restage
        for (int idx = threadIdx.x; idx < 128 * 16; idx += 256) {
            int r = idx >> 4, ch = idx & 15;
            uint4 v = ((const uint4*)(Wt + (size_t)(half * 128 + r) * D))[ch];
            *(uint4*)&Bs[r * 136 + ch * 8] = v;
        }
        __syncthreads();
        __hip_bfloat16* outp = half ? part1 : part0;
        for (int c = 0; c < 8; c++) {
            f32x4 acc = {0.f, 0.f, 0.f, 0.f};
            const unsigned short* brow = &Bs[(c * 16 + n15) * 136 + quad * 8];
#pragma unroll
            for (int t = 0; t < 4; t++)
                acc = __builtin_amdgcn_mfma_f32_16x16x32_bf16(
                    af[t], *(const bf16x8*)(brow + t * 32), acc, 0, 0, 0);
            int col = c * 16 + n15;
            float b = half ? __bfloat162float(bias[col]) : 0.f;
#pragma unroll
            for (int i = 0; i < 4; i++) {
                int row = n0 + w * 16 + quad * 4 + i;
                if (row < N) outp[(size_t)row * D + col] = __float2bfloat16(acc[i] + b);
            }
        }
    }
}

// ---- MFMA final: A AND B staged in LDS per matrix (measured best final
// variant, r2: 52us). out = sum_m tanh(S_m@W_m+b_m)
__global__ __launch_bounds__(256) void final_mfma_kernel(
    const __hip_bfloat16* __restrict__ X, const __hip_bfloat16* __restrict__ Agg,
    const __hip_bfloat16* __restrict__ Mn,
    const unsigned short* __restrict__ Wt1, const __hip_bfloat16* __restrict__ b1,
    const unsigned short* __restrict__ Wt2, const __hip_bfloat16* __restrict__ b2,
    const unsigned short* __restrict__ Wt3, const __hip_bfloat16* __restrict__ b3,
    void* __restrict__ out, const int* __restrict__ flag, int N) {
    __shared__ __align__(16) unsigned short As[64 * 136];
    __shared__ __align__(16) unsigned short Bs[128 * 136];
    int n0 = blockIdx.x * 64;
    int w = threadIdx.x >> 6, lane = threadIdx.x & 63;
    int n15 = lane & 15, quad = lane >> 4;
    float osum[8][4];
#pragma unroll
    for (int c = 0; c < 8; c++)
#pragma unroll
        for (int i = 0; i < 4; i++) osum[c][i] = 0.f;
    const __hip_bfloat16* srcs[3] = {X, Agg, Mn};
    const unsigned short* Wts[3] = {Wt1, Wt2, Wt3};
    const __hip_bfloat16* bs[3] = {b1, b2, b3};
    for (int m = 0; m < 3; m++) {
        if (m > 0) __syncthreads();  // prev iter's reads complete
        const __hip_bfloat16* S = srcs[m];
        const unsigned short* Wm = Wts[m];
        for (int idx = threadIdx.x; idx < 64 * 16; idx += 256) {
            int r = idx >> 4, ch = idx & 15;
            uint4 v = make_uint4(0u, 0u, 0u, 0u);
            int n = n0 + r;
            if (n < N) v = ((const uint4*)(S + (size_t)n * D))[ch];
            *(uint4*)&As[r * 136 + ch * 8] = v;
        }
        for (int idx = threadIdx.x; idx < 128 * 16; idx += 256) {
            int r = idx >> 4, ch = idx & 15;
            uint4 v = ((const uint4*)(Wm + (size_t)r * D))[ch];
            *(uint4*)&Bs[r * 136 + ch * 8] = v;
        }
        __syncthreads();
        const unsigned short* arow = &As[(w * 16 + n15) * 136 + quad * 8];
        bf16x8 af[4];
#pragma unroll
        for (int t = 0; t < 4; t++) af[t] = *(const bf16x8*)(arow + t * 32);
        for (int c = 0; c < 8; c++) {
            f32x4 acc = {0.f, 0.f, 0.f, 0.f};
            const unsigned short* brow = &Bs[(c * 16 + n15) * 136 + quad * 8];
#pragma unroll
            for (int t = 0; t < 4; t++)
                acc = __builtin_amdgcn_mfma_f32_16x16x32_bf16(
                    af[t], *(const bf16x8*)(brow + t * 32), acc, 0, 0, 0);
            float bb = __bfloat162float(bs[m][c * 16 + n15]);
#pragma unroll
            for (int i = 0; i < 4; i++) osum[c][i] += tanh_fast(acc[i] + bb);
        }
    }
    int f = flag[0];
    for (int c = 0; c < 8; c++) {
        int col = c * 16 + n15;
#pragma unroll
        for (int i = 0; i < 4; i++) {
            int row = n0 + w * 16 + quad * 4 + i;
            if (row < N) {
                if (f) ((float*)out)[(size_t)row * D + col] = osum[c][i];
                else   ((__hip_bfloat16*)out)[(size_t)row * D + col] =
                           __float2bfloat16(osum[c][i]);
            }
        }
    }
}

// Per-NODE edge scores: 16 lanes per node, loop over its CSR segment.
// Pkey row = the node's own row (key implied!) -- loaded and converted ONCE
// per segment instead of once per edge (avg degree 5 => ~5x less Pkey
// traffic + per-edge bf2f hoisted). 2x-unrolled edge loop; lane0 stores
// eij sequentially within the segment.
__global__ __launch_bounds__(256) void edge_score_kernel(
    const __hip_bfloat16* __restrict__ Pkey,
    const __hip_bfloat16* __restrict__ Poth,
    const int* __restrict__ ip,
    const int* __restrict__ oth,
    const __hip_bfloat16* __restrict__ w,
    const __hip_bfloat16* __restrict__ wb,
    float* __restrict__ eij, int N) {
    int g = (int)((blockIdx.x * 256 + threadIdx.x) >> 4);
    int l = threadIdx.x & 15;
    if (g >= N) return;
    int s0 = ip[g], s1 = ip[g + 1];
    if (s1 == s0) return;
    u16x8 wv = *(const u16x8*)((const unsigned short*)w + l * 8);
    float wf[8];
#pragma unroll
    for (int j = 0; j < 8; j++) wf[j] = bf2f(wv[j]);
    float wbv = bf2f(*(const unsigned short*)wb);
    const unsigned short* PK = (const unsigned short*)Pkey;
    const unsigned short* PO = (const unsigned short*)Poth;
    u16x8 a = *(const u16x8*)(PK + (size_t)g * D + l * 8);
    float av[8];
#pragma unroll
    for (int j = 0; j < 8; j++) av[j] = bf2f(a[j]);
    int i = s0;
    for (; i + 2 <= s1; i += 2) {
        int o0 = oth[i], o1 = oth[i + 1];
        u16x8 b0 = *(const u16x8*)(PO + (size_t)o0 * D + l * 8);
        u16x8 b1 = *(const u16x8*)(PO + (size_t)o1 * D + l * 8);
        float p0 = 0.f, p1 = 0.f;
#pragma unroll
        for (int j = 0; j < 8; j++) {
            p0 = fmaf(tanh_fast(av[j] + bf2f(b0[j])), wf[j], p0);
            p1 = fmaf(tanh_fast(av[j] + bf2f(b1[j])), wf[j], p1);
        }
        p0 += SWZ_F(p0, 0x041F); p1 += SWZ_F(p1, 0x041F);
        p0 += SWZ_F(p0, 0x081F); p1 += SWZ_F(p1, 0x081F);
        p0 += SWZ_F(p0, 0x101F); p1 += SWZ_F(p1, 0x101F);
        p0 += SWZ_F(p0, 0x201F); p1 += SWZ_F(p1, 0x201F);
        if (l == 0) { eij[i] = p0 + wbv; eij[i + 1] = p1 + wbv; }
    }
    if (i < s1) {
        int o0 = oth[i];
        u16x8 b0 = *(const u16x8*)(PO + (size_t)o0 * D + l * 8);
        float p0 = 0.f;
#pragma unroll
        for (int j = 0; j < 8; j++)
            p0 = fmaf(tanh_fast(av[j] + bf2f(b0[j])), wf[j], p0);
        p0 += SWZ_F(p0, 0x041F);
        p0 += SWZ_F(p0, 0x081F);
        p0 += SWZ_F(p0, 0x101F);
        p0 += SWZ_F(p0, 0x201F);
        if (l == 0) eij[i] = p0 + wbv;
    }
}

// ---- fused node aggregation: y=0 attn softmax-gather, y=1 mean gather.
// 16 lanes per node (8 elems/lane), 4 nodes/wave, 4x-unrolled gathers.
__global__ __launch_bounds__(256) void node_agg_kernel(
    const __hip_bfloat16* __restrict__ X,
    const float* __restrict__ eij_e, const int* __restrict__ ip_e,
    const int* __restrict__ oth_e,
    const float* __restrict__ eij_r, const int* __restrict__ ip_r,
    const int* __restrict__ oth_r,
    const int* __restrict__ ip_ee, const int* __restrict__ dst_ee,
    const int* __restrict__ ip_rr, const int* __restrict__ dst_rr,
    __hip_bfloat16* __restrict__ attn_agg,
    __hip_bfloat16* __restrict__ mean_agg, int N) {
    int g = (int)((blockIdx.x * 256 + threadIdx.x) >> 4);
    int l = threadIdx.x & 15;
    if (g >= N) return;
    const unsigned short* Xp = (const unsigned short*)X;
    float acc[8];
#pragma unroll
    for (int j = 0; j < 8; j++) acc[j] = 0.f;
    if (blockIdx.y == 0) {
        for (int side = 0; side < 2; side++) {
            const float* eij = side ? eij_r : eij_e;
            const int* ip  = side ? ip_r  : ip_e;
            const int* oth = side ? oth_r : oth_e;
            int s0 = ip[g], s1 = ip[g + 1];
            if (s1 == s0) continue;
            float m = 0.f;  // torch amax include_self over zeros => floor at 0
            for (int i = s0 + l; i < s1; i += 16) m = fmaxf(m, eij[i]);
            m = fmaxf(m, SWZ_F(m, 0x041F));
            m = fmaxf(m, SWZ_F(m, 0x081F));
            m = fmaxf(m, SWZ_F(m, 0x101F));
            m = fmaxf(m, SWZ_F(m, 0x201F));
            float ssum = 0.f;
            for (int i = s0 + l; i < s1; i += 16) ssum += __expf(eij[i] - m);
            ssum += SWZ_F(ssum, 0x041F);
            ssum += SWZ_F(ssum, 0x081F);
            ssum += SWZ_F(ssum, 0x101F);
            ssum += SWZ_F(ssum, 0x201F);
            float inv = 1.f / (ssum + 1e-9f);
            int i = s0;
            for (; i + 4 <= s1; i += 4) {
                int o0 = oth[i], o1 = oth[i + 1], o2 = oth[i + 2], o3 = oth[i + 3];
                u16x8 x0 = *(const u16x8*)(Xp + (size_t)o0 * D + l * 8);
                u16x8 x1 = *(const u16x8*)(Xp + (size_t)o1 * D + l * 8);
                u16x8 x2 = *(const u16x8*)(Xp + (size_t)o2 * D + l * 8);
                u16x8 x3 = *(const u16x8*)(Xp + (size_t)o3 * D + l * 8);
                float p0 = __expf(eij[i] - m) * inv;
                float p1 = __expf(eij[i + 1] - m) * inv;
                float p2 = __expf(eij[i + 2] - m) * inv;
                float p3 = __expf(eij[i + 3] - m) * inv;
#pragma unroll
                for (int j = 0; j < 8; j++)
                    acc[j] += p0 * bf2f(x0[j]) + p1 * bf2f(x1[j])
                            + p2 * bf2f(x2[j]) + p3 * bf2f(x3[j]);
            }
            for (; i < s1; i++) {
                int o0 = oth[i];
                u16x8 x0 = *(const u16x8*)(Xp + (size_t)o0 * D + l * 8);
                float p0 = __expf(eij[i] - m) * inv;
#pragma unroll
                for (int j = 0; j < 8; j++) acc[j] += p0 * bf2f(x0[j]);
            }
        }
        u16x8 ov;
#pragma unroll
        for (int j = 0; j < 8; j++) ov[j] = f2bf_u16(acc[j]);
        *(u16x8*)((unsigned short*)attn_agg + (size_t)g * D + l * 8) = ov;
    } else {
        int cnt = 0;
        for (int side = 0; side < 2; side++) {
            const int* ip  = side ? ip_rr  : ip_ee;
            const int* dst = side ? dst_rr : dst_ee;
            int s0 = ip[g], s1 = ip[g + 1];
            cnt += s1 - s0;
            int i = s0;
            for (; i + 4 <= s1; i += 4) {
                int o0 = dst[i], o1 = dst[i + 1], o2 = dst[i + 2], o3 = dst[i + 3];
                u16x8 x0 = *(const u16x8*)(Xp + (size_t)o0 * D + l * 8);
                u16x8 x1 = *(const u16x8*)(Xp + (size_t)o1 * D + l * 8);
                u16x8 x2 = *(const u16x8*)(Xp + (size_t)o2 * D + l * 8);
                u16x8 x3 = *(const u16x8*)(Xp + (size_t)o3 * D + l * 8);
#pragma unroll
                for (int j = 0; j < 8; j++)
                    acc[j] += (bf2f(x0[j]) + bf2f(x1[j]))
                            + (bf2f(x2[j]) + bf2f(x3[j]));
            }
            for (; i < s1; i++) {
                u16x8 x0 = *(const u16x8*)(Xp + (size_t)dst[i] * D + l * 8);
#pragma unroll
                for (int j = 0; j < 8; j++) acc[j] += bf2f(x0[j]);
            }
        }
        float inv = 1.f / fmaxf((float)cnt, 1.f);
        u16x8 ov;
#pragma unroll
        for (int j = 0; j < 8; j++) ov[j] = f2bf_u16(acc[j] * inv);
        *(u16x8*)((unsigned short*)mean_agg + (size_t)g * D + l * 8) = ov;
    }
}

extern "C" void kernel_launch(void* const* d_in, const int* in_sizes, int n_in,
                              void* d_out, int out_size, void* d_ws, size_t ws_size,
                              hipStream_t stream) {
    const int* er_src = (const int*)d_in[15];
    const int* er_dst = (const int*)d_in[16];
    const int* ee_src = (const int*)d_in[17];
    const int* ee_dst = (const int*)d_in[18];
    const int* rr_src = (const int*)d_in[19];
    const int* rr_dst = (const int*)d_in[20];

    int N   = in_sizes[0] / D;
    int Eer = in_sizes[15];
    int Eee = in_sizes[17];
    int Err = in_sizes[19];

    char* ws = (char*)d_ws;
    size_t off = 0;
    auto alloc = [&](size_t bytes) -> void* {
        void* p = ws + off;
        off = (off + bytes + 255) & ~(size_t)255;
        return p;
    };
    int ntpa = (N + TILE - 1) / TILE;
    int T = 4 * ntpa;
    int* flag   = (int*)alloc(256);
    int* oth_e  = (int*)alloc((size_t)Eer * 4);
    int* oth_r  = (int*)alloc((size_t)Eer * 4);
    int* dst_ee = (int*)alloc((size_t)Eee * 4);
    int* dst_rr = (int*)alloc((size_t)Err * 4);
    int* indptr = (int*)alloc((size_t)4 * (N + 1) * 4);
    int* degcur = (int*)alloc((size_t)4 * N * 4);
    int* tsum   = (int*)alloc((size_t)T * 4);
    int* toff   = (int*)alloc((size_t)T * 4);
    float* eij_e = (float*)alloc((size_t)Eer * 4);
    float* eij_r = (float*)alloc((size_t)Eer * 4);
    __hip_bfloat16* Xc = (__hip_bfloat16*)alloc((size_t)N * D * 2);
    __hip_bfloat16* part0 = (__hip_bfloat16*)alloc((size_t)N * D * 2);
    __hip_bfloat16* part1 = (__hip_bfloat16*)alloc((size_t)N * D * 2);
    __hip_bfloat16* attn_agg = part0;  // parts die after 2nd edge_score
    __hip_bfloat16* mean_agg = part1;
    unsigned short* WtA = (unsigned short*)alloc((size_t)256 * 128 * 2);
    unsigned short* WtR = (unsigned short*)alloc((size_t)256 * 128 * 2);
    unsigned short* Wt1 = (unsigned short*)alloc((size_t)128 * 128 * 2);
    unsigned short* Wt2 = (unsigned short*)alloc((size_t)128 * 128 * 2);
    unsigned short* Wt3 = (unsigned short*)alloc((size_t)128 * 128 * 2);
    ConvBatch cb;
    int widx[14] = {1, 2, 3, 4, 5, 6, 7, 8, 9, 10, 11, 12, 13, 14};
    for (int i = 0; i < 14; i++) {
        cb.src[i] = d_in[widx[i]];
        cb.n[i] = in_sizes[widx[i]];
        cb.dst[i] = (__hip_bfloat16*)alloc((size_t)cb.n[i] * 2);
    }
    const __hip_bfloat16* bae = cb.dst[1];
    const __hip_bfloat16* w0w = cb.dst[2];
    const __hip_bfloat16* w0b = cb.dst[3];
    const __hip_bfloat16* bar_= cb.dst[5];
    const __hip_bfloat16* w1w = cb.dst[6];
    const __hip_bfloat16* w1b = cb.dst[7];
    const __hip_bfloat16* b1  = cb.dst[9];
    const __hip_bfloat16* b2  = cb.dst[11];
    const __hip_bfloat16* b3  = cb.dst[13];
    (void)n_in; (void)out_size;
    if (off > ws_size) return;  // diagnostic: zeros => absmax ~2.58, not NaN

    // ---- dtype detect + canonicalize ----
    detect_kernel<<<1, 256, 0, stream>>>((const unsigned short*)d_in[0], flag);
    conv_weights_kernel<<<dim3(32, 14), 256, 0, stream>>>(cb, flag);
    conv_x_kernel<<<(N * D / 4 + 255) / 256, 256, 0, stream>>>(d_in[0], Xc, N * D, flag);
    TransBatch tb;
    tb.base[0] = d_in[1];  tb.off[0] = 0;         tb.dst[0] = WtA;
    tb.base[1] = d_in[1];  tb.off[1] = 128 * 128; tb.dst[1] = WtA + 128 * 128;
    tb.base[2] = d_in[5];  tb.off[2] = 0;         tb.dst[2] = WtR;
    tb.base[3] = d_in[5];  tb.off[3] = 128 * 128; tb.dst[3] = WtR + 128 * 128;
    tb.base[4] = d_in[9];  tb.off[4] = 0;         tb.dst[4] = Wt1;
    tb.base[5] = d_in[11]; tb.off[5] = 0;         tb.dst[5] = Wt2;
    tb.base[6] = d_in[13]; tb.off[6] = 0;         tb.dst[6] = Wt3;
    trans_kernel<<<dim3(16, 7), 256, 0, stream>>>(tb, flag);

    // ---- CSR build (4 keys: er_src, er_dst, ee_src, rr_src) ----
    zero_kernel<<<(4 * N + 255) / 256, 256, 0, stream>>>(degcur, 4 * N);
    int Emax = Eer > Eee ? Eer : Eee;
    if (Err > Emax) Emax = Err;
    count4_kernel<<<dim3((Emax + 255) / 256, 4), 256, 0, stream>>>(
        er_src, er_dst, ee_src, rr_src, Eer, Eer, Eee, Err, degcur, N);
    scan_partial_kernel<<<T, 256, 0, stream>>>(degcur, tsum, N, ntpa);
    scan_tiles_kernel<<<1, 256, 0, stream>>>(tsum, toff, indptr, N, ntpa);
    scan_final_kernel<<<T, 256, 0, stream>>>(degcur, toff, indptr, N, ntpa);
    scatter4_kernel<<<dim3((Emax + 255) / 256, 4), 256, 0, stream>>>(
        er_src, er_dst, er_dst, er_src, ee_src, ee_dst, rr_src, rr_dst,
        Eer, Eer, Eee, Err, degcur, N, oth_e, oth_r, dst_ee, dst_rr);

    int GB = (N + 63) / 64;
    int NG = (N + 15) / 16;  // 16 lanes per node, 16 nodes per block

    // entity side: pair=[r,h]@Wae; key=src(h part,+bae), oth=dst(r part)
    gemm2_mfma_kernel<<<GB, 256, 0, stream>>>(Xc, WtA, bae, part0, part1, N);
    edge_score_kernel<<<NG, 256, 0, stream>>>(part1, part0, indptr, oth_e,
                                              w0w, w0b, eij_e, N);

    // relation side: pair=[h,r]@War; key=dst(r part,+bar), oth=src(h part)
    gemm2_mfma_kernel<<<GB, 256, 0, stream>>>(Xc, WtR, bar_, part0, part1, N);
    edge_score_kernel<<<NG, 256, 0, stream>>>(part1, part0, indptr + (N + 1), oth_r,
                                              w1w, w1b, eij_r, N);

    node_agg_kernel<<<dim3(NG, 2), 256, 0, stream>>>(
        Xc, eij_e, indptr, oth_e, eij_r, indptr + (N + 1), oth_r,
        indptr + 2 * (N + 1), dst_ee, indptr + 3 * (N + 1), dst_rr,
        attn_agg, mean_agg, N);
    final_mfma_kernel<<<GB, 256, 0, stream>>>(Xc, attn_agg, mean_agg,
                                              Wt1, b1, Wt2, b2, Wt3, b3,
                                              d_out, flag, N);
}

// Round 15
// 552.024 us; speedup vs baseline: 1.0618x; 1.0618x over previous
//
#include <hip/hip_runtime.h>
#include <hip/hip_bf16.h>

#define D 128
#define TILE 2048
// LDS row pitch 136 u16 = 272B = 17x16B: 16B-aligned rows (REQUIRED for b128
// ops -- 132 broke alignment on odd rows and cost +73% despite fewer counted
// bank conflicts, measured r9).

typedef __bf16 bf16x8 __attribute__((ext_vector_type(8)));
typedef float f32x4 __attribute__((ext_vector_type(4)));
typedef unsigned short u16x8 __attribute__((ext_vector_type(8)));

// fast tanh: 1 - 2/(e^{2|x|}+1), sign-restored. v_exp + v_rcp, branch-free,
// saturates to +-1 for large |x|. ~1e-6 rel err.
__device__ __forceinline__ float tanh_fast(float x) {
    float e = __expf(2.0f * fabsf(x));
    float t = 1.0f - 2.0f * __builtin_amdgcn_rcpf(e + 1.0f);
    return copysignf(t, x);
}

__device__ __forceinline__ float bf2f(unsigned short u) {
    return __uint_as_float((unsigned int)u << 16);
}

__device__ __forceinline__ unsigned short f2bf_u16(float x) {
    __hip_bfloat16 t = __float2bfloat16(x);
    return *(unsigned short*)&t;
}

// ds_swizzle BitMode xor-butterfly within 16-lane groups (masks 1,2,4,8).
#define SWZ_F(x, imm) __int_as_float(__builtin_amdgcn_ds_swizzle(__float_as_int(x), imm))

// ---- dtype detection: are float inputs f32 or bf16 on device? flag=1 => f32.
__global__ __launch_bounds__(256) void detect_kernel(const unsigned short* __restrict__ x,
                                                     int* __restrict__ flag) {
    int t = threadIdx.x;
    int cnt = 0;
    for (int i = t; i < 4096; i += 256) {
        unsigned e = (x[i] >> 7) & 0xFFu;
        if (e == 0xFFu || e >= 0x90u || (e >= 1u && e <= 0x6Eu)) cnt++;
    }
    __shared__ int sh[256];
    sh[t] = cnt;
    __syncthreads();
    for (int off = 128; off; off >>= 1) {
        if (t < off) sh[t] += sh[t + off];
        __syncthreads();
    }
    if (t == 0) flag[0] = (sh[0] > 800) ? 1 : 0;
}

struct ConvBatch {
    const void* src[14];
    __hip_bfloat16* dst[14];
    int n[14];
};

// grid = (32, 14): blockIdx.y picks the array, 4 elems/thread vectorized.
__global__ __launch_bounds__(256) void conv_weights_kernel(ConvBatch cb,
                                                           const int* __restrict__ flag) {
    int a = blockIdx.y;
    const void* s = cb.src[a];
    unsigned short* d = (unsigned short*)cb.dst[a];
    int n = cb.n[a];
    int f = flag[0];
    int i = (blockIdx.x * 256 + threadIdx.x) * 4;
    if (i >= n) return;
    if (i + 4 <= n) {
        ushort4 o;
        if (f) {
            float4 v = *(const float4*)((const float*)s + i);
            o.x = f2bf_u16(v.x); o.y = f2bf_u16(v.y);
            o.z = f2bf_u16(v.z); o.w = f2bf_u16(v.w);
        } else {
            o = *(const ushort4*)((const unsigned short*)s + i);
        }
        *(ushort4*)(d + i) = o;
    } else {
        for (int j = i; j < n; j++)
            d[j] = f ? f2bf_u16(((const float*)s)[j])
                     : ((const unsigned short*)s)[j];
    }
}

// 4 elems/thread vectorized; n is a multiple of 4 (N*D).
__global__ __launch_bounds__(256) void conv_x_kernel(const void* __restrict__ src,
                                                     __hip_bfloat16* __restrict__ dst,
                                                     int n, const int* __restrict__ flag) {
    int i = (blockIdx.x * 256 + threadIdx.x) * 4;
    if (i >= n) return;
    int f = flag[0];
    ushort4 o;
    if (f) {
        float4 v = *(const float4*)((const float*)src + i);
        o.x = f2bf_u16(v.x); o.y = f2bf_u16(v.y);
        o.z = f2bf_u16(v.z); o.w = f2bf_u16(v.w);
    } else {
        o = *(const ushort4*)((const unsigned short*)src + i);
    }
    *(ushort4*)((unsigned short*)dst + i) = o;
}

// ---- weight transpose: 7 independent 128x128 blocks -> Wt[c][k] = W[k][c] (bf16)
struct TransBatch {
    const void* base[7];
    int off[7];
    unsigned short* dst[7];
};

// grid = (16, 7): blockIdx.y picks the matrix; 4 consecutive elems/thread
// (same source row), vectorized source read, 4 strided u16 stores.
__global__ __launch_bounds__(256) void trans_kernel(TransBatch tb,
                                                    const int* __restrict__ flag) {
    int a = blockIdx.y;
    int f = flag[0];
    const float* sf = (const float*)tb.base[a] + tb.off[a];
    const unsigned short* sb = (const unsigned short*)tb.base[a] + tb.off[a];
    unsigned short* d = tb.dst[a];
    int idx = (blockIdx.x * 256 + threadIdx.x) * 4;  // < 128*128
    int k = idx >> 7, c = idx & 127;
    unsigned short v[4];
    if (f) {
        float4 x = *(const float4*)(sf + idx);
        v[0] = f2bf_u16(x.x); v[1] = f2bf_u16(x.y);
        v[2] = f2bf_u16(x.z); v[3] = f2bf_u16(x.w);
    } else {
        ushort4 x = *(const ushort4*)(sb + idx);
        v[0] = x.x; v[1] = x.y; v[2] = x.z; v[3] = x.w;
    }
#pragma unroll
    for (int j = 0; j < 4; j++) d[(c + j) * 128 + k] = v[j];
}

__global__ __launch_bounds__(256) void zero_kernel(int* p, int n) {
    int i = blockIdx.x * 256 + threadIdx.x;
    if (i < n) p[i] = 0;
}

// ---- fused degree count for 4 key arrays; grid = (maxE/256, 4).
__global__ __launch_bounds__(256) void count4_kernel(const int* __restrict__ k0,
                                                     const int* __restrict__ k1,
                                                     const int* __restrict__ k2,
                                                     const int* __restrict__ k3,
                                                     int E0, int E1, int E2, int E3,
                                                     int* __restrict__ deg, int N) {
    int y = blockIdx.y;
    const int* k = (y == 0) ? k0 : (y == 1) ? k1 : (y == 2) ? k2 : k3;
    int E = (y == 0) ? E0 : (y == 1) ? E1 : (y == 2) ? E2 : E3;
    int i = blockIdx.x * 256 + threadIdx.x;
    if (i < E) atomicAdd(&deg[y * N + k[i]], 1);
}

// ---- hierarchical scan, phase 1: per-tile sums. grid = 4 * ntpa blocks.
__global__ __launch_bounds__(256) void scan_partial_kernel(const int* __restrict__ deg,
                                                           int* __restrict__ tsum,
                                                           int N, int ntpa) {
    int a = blockIdx.x / ntpa, t = blockIdx.x % ntpa;
    const int* d = deg + (size_t)a * N + (size_t)t * TILE;
    int lim = N - t * TILE; if (lim > TILE) lim = TILE;
    int base = threadIdx.x * 8;
    int s = 0;
#pragma unroll
    for (int j = 0; j < 8; j++) {
        int i = base + j;
        if (i < lim) s += d[i];
    }
    __shared__ int sh[256];
    sh[threadIdx.x] = s;
    __syncthreads();
    for (int off = 128; off; off >>= 1) {
        if (threadIdx.x < off) sh[threadIdx.x] += sh[threadIdx.x + off];
        __syncthreads();
    }
    if (threadIdx.x == 0) tsum[blockIdx.x] = sh[0];
}

// ---- phase 2: exclusive scan of tile sums per array (ntpa <= 256); one block.
__global__ __launch_bounds__(256) void scan_tiles_kernel(const int* __restrict__ tsum,
                                                         int* __restrict__ toff,
                                                         int* __restrict__ indptr,
                                                         int N, int ntpa) {
    __shared__ int tmp[256];
    int t = threadIdx.x;
    for (int a = 0; a < 4; a++) {
        int v = (t < ntpa) ? tsum[a * ntpa + t] : 0;
        tmp[t] = v;
        __syncthreads();
        for (int off = 1; off < 256; off <<= 1) {
            int u = (t >= off) ? tmp[t - off] : 0;
            __syncthreads();
            tmp[t] += u;
            __syncthreads();
        }
        if (t < ntpa) toff[a * ntpa + t] = tmp[t] - v;  // exclusive
        if (t == ntpa - 1) indptr[(size_t)a * (N + 1) + N] = tmp[t];
        __syncthreads();
    }
}

// ---- phase 3: intra-tile scan + tile offset; writes indptr and cursor.
__global__ __launch_bounds__(256) void scan_final_kernel(int* __restrict__ degcur,
                                                         const int* __restrict__ toff,
                                                         int* __restrict__ indptr,
                                                         int N, int ntpa) {
    int a = blockIdx.x / ntpa, t = blockIdx.x % ntpa;
    int* d = degcur + (size_t)a * N + (size_t)t * TILE;
    int* ip = indptr + (size_t)a * (N + 1) + (size_t)t * TILE;
    int lim = N - t * TILE; if (lim > TILE) lim = TILE;
    int base = threadIdx.x * 8;
    int v[8];
    int s = 0;
#pragma unroll
    for (int j = 0; j < 8; j++) {
        int i = base + j;
        v[j] = (i < lim) ? d[i] : 0;
        s += v[j];
    }
    __shared__ int tmp[256];
    tmp[threadIdx.x] = s;
    __syncthreads();
    for (int off = 1; off < 256; off <<= 1) {
        int u = (threadIdx.x >= off) ? tmp[threadIdx.x - off] : 0;
        __syncthreads();
        tmp[threadIdx.x] += u;
        __syncthreads();
    }
    int run = toff[blockIdx.x] + tmp[threadIdx.x] - s;
#pragma unroll
    for (int j = 0; j < 8; j++) {
        int i = base + j;
        if (i < lim) { ip[i] = run; d[i] = run; run += v[j]; }
    }
}

// ---- fused attention-side scatter (both directions); grid = (Eer/256, 2).
// key+oth written as ONE int2 (8B) to one array: one dirty cache line per
// edge instead of two (r11: WRITE_SIZE 110MB for 8MB payload = line-bound;
// r14 confirmed 4B payloads dirty the same lines -- this is the floor).
__global__ __launch_bounds__(256) void scatter_attn2_kernel(const int* __restrict__ er_src,
                                                            const int* __restrict__ er_dst, int E,
                                                            int* __restrict__ cursor, int N,
                                                            int2* __restrict__ koth_e,
                                                            int2* __restrict__ koth_r) {
    int y = blockIdx.y;
    int i = blockIdx.x * 256 + threadIdx.x;
    if (i >= E) return;
    const int* keys = y ? er_dst : er_src;
    const int* oths = y ? er_src : er_dst;
    int* cur = cursor + (size_t)y * N;
    int2* ko = y ? koth_r : koth_e;
    int k = keys[i];
    int p = atomicAdd(&cur[k], 1);
    ko[p] = make_int2(k, oths[i]);
}

// ---- fused mean-side scatter (ee and rr); grid = (maxE/256, 2).
__global__ __launch_bounds__(256) void scatter_mean2_kernel(const int* __restrict__ ee_src,
                                                            const int* __restrict__ ee_dst, int Eee,
                                                            const int* __restrict__ rr_src,
                                                            const int* __restrict__ rr_dst, int Err,
                                                            int* __restrict__ cursor, int N,
                                                            int* __restrict__ dst_ee,
                                                            int* __restrict__ dst_rr) {
    int y = blockIdx.y;
    const int* keys = y ? rr_src : ee_src;
    const int* dsts = y ? rr_dst : ee_dst;
    int E = y ? Err : Eee;
    int* cur = cursor + (size_t)(2 + y) * N;
    int* ds = y ? dst_rr : dst_ee;
    int i = blockIdx.x * 256 + threadIdx.x;
    if (i < E) {
        int p = atomicAdd(&cur[keys[i]], 1);
        ds[p] = dsts[i];
    }
}

// ---- MFMA GEMM: B staged in LDS per 128-col half; A fragments direct from
// global per wave (dense guarded 64B segments) -- no A stage, no A barrier.
// (Measured best gemm2 variant, r6.)
__global__ __launch_bounds__(256) void gemm2_mfma_kernel(
    const __hip_bfloat16* __restrict__ X,
    const unsigned short* __restrict__ Wt,      // 256 x 128, Wt[c][k]
    const __hip_bfloat16* __restrict__ bias,    // 128 (part1 only)
    __hip_bfloat16* __restrict__ part0,
    __hip_bfloat16* __restrict__ part1, int N) {
    __shared__ __align__(16) unsigned short Bs[128 * 136];
    int n0 = blockIdx.x * 64;
    int w = threadIdx.x >> 6, lane = threadIdx.x & 63;
    int n15 = lane & 15, quad = lane >> 4;
    int arow = n0 + w * 16 + n15;
    const unsigned short* ap = (const unsigned short*)X + (size_t)arow * D + quad * 8;
    bf16x8 af[4];
#pragma unroll
    for (int t = 0; t < 4; t++) {
        bf16x8 v = {};
        if (arow < N) v = *(const bf16x8*)(ap + t * 32);
        af[t] = v;
    }
    for (int half = 0; half < 2; half++) {
        if (half) __syncthreads();  // all reads of Bs done before restage
        for (int idx = threadIdx.x; idx < 128 * 16; idx += 256) {
            int r = idx >> 4, ch = idx & 15;
            uint4 v = ((const uint4*)(Wt + (size_t)(half * 128 + r) * D))[ch];
            *(uint4*)&Bs[r * 136 + ch * 8] = v;
        }
        __syncthreads();
        __hip_bfloat16* outp = half ? part1 : part0;
        for (int c = 0; c < 8; c++) {
            f32x4 acc = {0.f, 0.f, 0.f, 0.f};
            const unsigned short* brow = &Bs[(c * 16 + n15) * 136 + quad * 8];
#pragma unroll
            for (int t = 0; t < 4; t++)
                acc = __builtin_amdgcn_mfma_f32_16x16x32_bf16(
                    af[t], *(const bf16x8*)(brow + t * 32), acc, 0, 0, 0);
            int col = c * 16 + n15;
            float b = half ? __bfloat162float(bias[col]) : 0.f;
#pragma unroll
            for (int i = 0; i < 4; i++) {
                int row = n0 + w * 16 + quad * 4 + i;
                if (row < N) outp[(size_t)row * D + col] = __float2bfloat16(acc[i] + b);
            }
        }
    }
}

// ---- MFMA final: A AND B staged in LDS per matrix (measured best final
// variant, r2: 52us -- A-stage loads issue early and hide under B-stage +
// barrier; A-direct after the barrier measured 60us, A-hoist-up-front 111us).
// out = sum_m tanh(S_m@W_m+b_m)
__global__ __launch_bounds__(256) void final_mfma_kernel(
    const __hip_bfloat16* __restrict__ X, const __hip_bfloat16* __restrict__ Agg,
    const __hip_bfloat16* __restrict__ Mn,
    const unsigned short* __restrict__ Wt1, const __hip_bfloat16* __restrict__ b1,
    const unsigned short* __restrict__ Wt2, const __hip_bfloat16* __restrict__ b2,
    const unsigned short* __restrict__ Wt3, const __hip_bfloat16* __restrict__ b3,
    void* __restrict__ out, const int* __restrict__ flag, int N) {
    __shared__ __align__(16) unsigned short As[64 * 136];
    __shared__ __align__(16) unsigned short Bs[128 * 136];
    int n0 = blockIdx.x * 64;
    int w = threadIdx.x >> 6, lane = threadIdx.x & 63;
    int n15 = lane & 15, quad = lane >> 4;
    float osum[8][4];
#pragma unroll
    for (int c = 0; c < 8; c++)
#pragma unroll
        for (int i = 0; i < 4; i++) osum[c][i] = 0.f;
    const __hip_bfloat16* srcs[3] = {X, Agg, Mn};
    const unsigned short* Wts[3] = {Wt1, Wt2, Wt3};
    const __hip_bfloat16* bs[3] = {b1, b2, b3};
    for (int m = 0; m < 3; m++) {
        if (m > 0) __syncthreads();  // prev iter's reads complete
        const __hip_bfloat16* S = srcs[m];
        const unsigned short* Wm = Wts[m];
        for (int idx = threadIdx.x; idx < 64 * 16; idx += 256) {
            int r = idx >> 4, ch = idx & 15;
            uint4 v = make_uint4(0u, 0u, 0u, 0u);
            int n = n0 + r;
            if (n < N) v = ((const uint4*)(S + (size_t)n * D))[ch];
            *(uint4*)&As[r * 136 + ch * 8] = v;
        }
        for (int idx = threadIdx.x; idx < 128 * 16; idx += 256) {
            int r = idx >> 4, ch = idx & 15;
            uint4 v = ((const uint4*)(Wm + (size_t)r * D))[ch];
            *(uint4*)&Bs[r * 136 + ch * 8] = v;
        }
        __syncthreads();
        const unsigned short* arow = &As[(w * 16 + n15) * 136 + quad * 8];
        bf16x8 af[4];
#pragma unroll
        for (int t = 0; t < 4; t++) af[t] = *(const bf16x8*)(arow + t * 32);
        for (int c = 0; c < 8; c++) {
            f32x4 acc = {0.f, 0.f, 0.f, 0.f};
            const unsigned short* brow = &Bs[(c * 16 + n15) * 136 + quad * 8];
#pragma unroll
            for (int t = 0; t < 4; t++)
                acc = __builtin_amdgcn_mfma_f32_16x16x32_bf16(
                    af[t], *(const bf16x8*)(brow + t * 32), acc, 0, 0, 0);
            float bb = __bfloat162float(bs[m][c * 16 + n15]);
#pragma unroll
            for (int i = 0; i < 4; i++) osum[c][i] += tanh_fast(acc[i] + bb);
        }
    }
    int f = flag[0];
    for (int c = 0; c < 8; c++) {
        int col = c * 16 + n15;
#pragma unroll
        for (int i = 0; i < 4; i++) {
            int row = n0 + w * 16 + quad * 4 + i;
            if (row < N) {
                if (f) ((float*)out)[(size_t)row * D + col] = osum[c][i];
                else   ((__hip_bfloat16*)out)[(size_t)row * D + col] =
                           __float2bfloat16(osum[c][i]);
            }
        }
    }
}

// CSR-ordered edge scores: 16 lanes per edge (8 elems/lane, 16B loads),
// 4 edges per wave, grid-stride persistent waves. key+oth read as one int2;
// 4-step ds_swizzle reduce; sequential coalesced eij store.
__global__ __launch_bounds__(256) void edge_score_kernel(
    const __hip_bfloat16* __restrict__ Pkey,
    const __hip_bfloat16* __restrict__ Poth,
    const int2* __restrict__ koth,
    const __hip_bfloat16* __restrict__ w,
    const __hip_bfloat16* __restrict__ wb,
    float* __restrict__ eij, int E) {
    int l = threadIdx.x & 15;
    int gid = (int)((blockIdx.x * 256 + threadIdx.x) >> 4);
    int ngroups = (int)((gridDim.x * 256) >> 4);
    u16x8 wv = *(const u16x8*)((const unsigned short*)w + l * 8);
    float wf[8];
#pragma unroll
    for (int j = 0; j < 8; j++) wf[j] = bf2f(wv[j]);
    float wbv = bf2f(*(const unsigned short*)wb);
    const unsigned short* PK = (const unsigned short*)Pkey;
    const unsigned short* PO = (const unsigned short*)Poth;
    for (int s = gid; s < E; s += ngroups) {
        int2 ko = koth[s];
        u16x8 a = *(const u16x8*)(PK + (size_t)ko.x * D + l * 8);
        u16x8 b = *(const u16x8*)(PO + (size_t)ko.y * D + l * 8);
        float p = 0.f;
#pragma unroll
        for (int j = 0; j < 8; j++)
            p = fmaf(tanh_fast(bf2f(a[j]) + bf2f(b[j])), wf[j], p);
        p += SWZ_F(p, 0x041F);
        p += SWZ_F(p, 0x081F);
        p += SWZ_F(p, 0x101F);
        p += SWZ_F(p, 0x201F);
        if (l == 0) eij[s] = p + wbv;
    }
}

// ---- fused node aggregation: y=0 attn softmax-gather, y=1 mean gather.
// 16 lanes per node (8 elems/lane), 4 nodes/wave, 4x-unrolled gathers.
__global__ __launch_bounds__(256) void node_agg_kernel(
    const __hip_bfloat16* __restrict__ X,
    const float* __restrict__ eij_e, const int* __restrict__ ip_e,
    const int2* __restrict__ koth_e,
    const float* __restrict__ eij_r, const int* __restrict__ ip_r,
    const int2* __restrict__ koth_r,
    const int* __restrict__ ip_ee, const int* __restrict__ dst_ee,
    const int* __restrict__ ip_rr, const int* __restrict__ dst_rr,
    __hip_bfloat16* __restrict__ attn_agg,
    __hip_bfloat16* __restrict__ mean_agg, int N) {
    int g = (int)((blockIdx.x * 256 + threadIdx.x) >> 4);
    int l = threadIdx.x & 15;
    if (g >= N) return;
    const unsigned short* Xp = (const unsigned short*)X;
    float acc[8];
#pragma unroll
    for (int j = 0; j < 8; j++) acc[j] = 0.f;
    if (blockIdx.y == 0) {
        for (int side = 0; side < 2; side++) {
            const float* eij = side ? eij_r : eij_e;
            const int* ip  = side ? ip_r  : ip_e;
            const int2* ko = side ? koth_r : koth_e;
            int s0 = ip[g], s1 = ip[g + 1];
            if (s1 == s0) continue;
            float m = 0.f;  // torch amax include_self over zeros => floor at 0
            for (int i = s0 + l; i < s1; i += 16) m = fmaxf(m, eij[i]);
            m = fmaxf(m, SWZ_F(m, 0x041F));
            m = fmaxf(m, SWZ_F(m, 0x081F));
            m = fmaxf(m, SWZ_F(m, 0x101F));
            m = fmaxf(m, SWZ_F(m, 0x201F));
            float ssum = 0.f;
            for (int i = s0 + l; i < s1; i += 16) ssum += __expf(eij[i] - m);
            ssum += SWZ_F(ssum, 0x041F);
            ssum += SWZ_F(ssum, 0x081F);
            ssum += SWZ_F(ssum, 0x101F);
            ssum += SWZ_F(ssum, 0x201F);
            float inv = 1.f / (ssum + 1e-9f);
            int i = s0;
            for (; i + 4 <= s1; i += 4) {
                int o0 = ko[i].y, o1 = ko[i + 1].y, o2 = ko[i + 2].y, o3 = ko[i + 3].y;
                u16x8 x0 = *(const u16x8*)(Xp + (size_t)o0 * D + l * 8);
                u16x8 x1 = *(const u16x8*)(Xp + (size_t)o1 * D + l * 8);
                u16x8 x2 = *(const u16x8*)(Xp + (size_t)o2 * D + l * 8);
                u16x8 x3 = *(const u16x8*)(Xp + (size_t)o3 * D + l * 8);
                float p0 = __expf(eij[i] - m) * inv;
                float p1 = __expf(eij[i + 1] - m) * inv;
                float p2 = __expf(eij[i + 2] - m) * inv;
                float p3 = __expf(eij[i + 3] - m) * inv;
#pragma unroll
                for (int j = 0; j < 8; j++)
                    acc[j] += p0 * bf2f(x0[j]) + p1 * bf2f(x1[j])
                            + p2 * bf2f(x2[j]) + p3 * bf2f(x3[j]);
            }
            for (; i < s1; i++) {
                int o0 = ko[i].y;
                u16x8 x0 = *(const u16x8*)(Xp + (size_t)o0 * D + l * 8);
                float p0 = __expf(eij[i] - m) * inv;
#pragma unroll
                for (int j = 0; j < 8; j++) acc[j] += p0 * bf2f(x0[j]);
            }
        }
        u16x8 ov;
#pragma unroll
        for (int j = 0; j < 8; j++) ov[j] = f2bf_u16(acc[j]);
        *(u16x8*)((unsigned short*)attn_agg + (size_t)g * D + l * 8) = ov;
    } else {
        int cnt = 0;
        for (int side = 0; side < 2; side++) {
            const int* ip  = side ? ip_rr  : ip_ee;
            const int* dst = side ? dst_rr : dst_ee;
            int s0 = ip[g], s1 = ip[g + 1];
            cnt += s1 - s0;
            int i = s0;
            for (; i + 4 <= s1; i += 4) {
                int o0 = dst[i], o1 = dst[i + 1], o2 = dst[i + 2], o3 = dst[i + 3];
                u16x8 x0 = *(const u16x8*)(Xp + (size_t)o0 * D + l * 8);
                u16x8 x1 = *(const u16x8*)(Xp + (size_t)o1 * D + l * 8);
                u16x8 x2 = *(const u16x8*)(Xp + (size_t)o2 * D + l * 8);
                u16x8 x3 = *(const u16x8*)(Xp + (size_t)o3 * D + l * 8);
#pragma unroll
                for (int j = 0; j < 8; j++)
                    acc[j] += (bf2f(x0[j]) + bf2f(x1[j]))
                            + (bf2f(x2[j]) + bf2f(x3[j]));
            }
            for (; i < s1; i++) {
                u16x8 x0 = *(const u16x8*)(Xp + (size_t)dst[i] * D + l * 8);
#pragma unroll
                for (int j = 0; j < 8; j++) acc[j] += bf2f(x0[j]);
            }
        }
        float inv = 1.f / fmaxf((float)cnt, 1.f);
        u16x8 ov;
#pragma unroll
        for (int j = 0; j < 8; j++) ov[j] = f2bf_u16(acc[j] * inv);
        *(u16x8*)((unsigned short*)mean_agg + (size_t)g * D + l * 8) = ov;
    }
}

extern "C" void kernel_launch(void* const* d_in, const int* in_sizes, int n_in,
                              void* d_out, int out_size, void* d_ws, size_t ws_size,
                              hipStream_t stream) {
    const int* er_src = (const int*)d_in[15];
    const int* er_dst = (const int*)d_in[16];
    const int* ee_src = (const int*)d_in[17];
    const int* ee_dst = (const int*)d_in[18];
    const int* rr_src = (const int*)d_in[19];
    const int* rr_dst = (const int*)d_in[20];

    int N   = in_sizes[0] / D;
    int Eer = in_sizes[15];
    int Eee = in_sizes[17];
    int Err = in_sizes[19];

    char* ws = (char*)d_ws;
    size_t off = 0;
    auto alloc = [&](size_t bytes) -> void* {
        void* p = ws + off;
        off = (off + bytes + 255) & ~(size_t)255;
        return p;
    };
    int ntpa = (N + TILE - 1) / TILE;
    int T = 4 * ntpa;
    int* flag   = (int*)alloc(256);
    int2* koth_e = (int2*)alloc((size_t)Eer * 8);
    int2* koth_r = (int2*)alloc((size_t)Eer * 8);
    int* dst_ee = (int*)alloc((size_t)Eee * 4);
    int* dst_rr = (int*)alloc((size_t)Err * 4);
    int* indptr = (int*)alloc((size_t)4 * (N + 1) * 4);
    int* degcur = (int*)alloc((size_t)4 * N * 4);
    int* tsum   = (int*)alloc((size_t)T * 4);
    int* toff   = (int*)alloc((size_t)T * 4);
    float* eij_e = (float*)alloc((size_t)Eer * 4);
    float* eij_r = (float*)alloc((size_t)Eer * 4);
    __hip_bfloat16* Xc = (__hip_bfloat16*)alloc((size_t)N * D * 2);
    __hip_bfloat16* part0 = (__hip_bfloat16*)alloc((size_t)N * D * 2);
    __hip_bfloat16* part1 = (__hip_bfloat16*)alloc((size_t)N * D * 2);
    __hip_bfloat16* attn_agg = part0;  // parts die after 2nd edge_score
    __hip_bfloat16* mean_agg = part1;
    unsigned short* WtA = (unsigned short*)alloc((size_t)256 * 128 * 2);
    unsigned short* WtR = (unsigned short*)alloc((size_t)256 * 128 * 2);
    unsigned short* Wt1 = (unsigned short*)alloc((size_t)128 * 128 * 2);
    unsigned short* Wt2 = (unsigned short*)alloc((size_t)128 * 128 * 2);
    unsigned short* Wt3 = (unsigned short*)alloc((size_t)128 * 128 * 2);
    ConvBatch cb;
    int widx[14] = {1, 2, 3, 4, 5, 6, 7, 8, 9, 10, 11, 12, 13, 14};
    for (int i = 0; i < 14; i++) {
        cb.src[i] = d_in[widx[i]];
        cb.n[i] = in_sizes[widx[i]];
        cb.dst[i] = (__hip_bfloat16*)alloc((size_t)cb.n[i] * 2);
    }
    const __hip_bfloat16* bae = cb.dst[1];
    const __hip_bfloat16* w0w = cb.dst[2];
    const __hip_bfloat16* w0b = cb.dst[3];
    const __hip_bfloat16* bar_= cb.dst[5];
    const __hip_bfloat16* w1w = cb.dst[6];
    const __hip_bfloat16* w1b = cb.dst[7];
    const __hip_bfloat16* b1  = cb.dst[9];
    const __hip_bfloat16* b2  = cb.dst[11];
    const __hip_bfloat16* b3  = cb.dst[13];
    (void)n_in; (void)out_size;
    if (off > ws_size) return;  // diagnostic: zeros => absmax ~2.58, not NaN

    // ---- dtype detect + canonicalize ----
    detect_kernel<<<1, 256, 0, stream>>>((const unsigned short*)d_in[0], flag);
    conv_weights_kernel<<<dim3(32, 14), 256, 0, stream>>>(cb, flag);
    conv_x_kernel<<<(N * D / 4 + 255) / 256, 256, 0, stream>>>(d_in[0], Xc, N * D, flag);
    TransBatch tb;
    tb.base[0] = d_in[1];  tb.off[0] = 0;         tb.dst[0] = WtA;
    tb.base[1] = d_in[1];  tb.off[1] = 128 * 128; tb.dst[1] = WtA + 128 * 128;
    tb.base[2] = d_in[5];  tb.off[2] = 0;         tb.dst[2] = WtR;
    tb.base[3] = d_in[5];  tb.off[3] = 128 * 128; tb.dst[3] = WtR + 128 * 128;
    tb.base[4] = d_in[9];  tb.off[4] = 0;         tb.dst[4] = Wt1;
    tb.base[5] = d_in[11]; tb.off[5] = 0;         tb.dst[5] = Wt2;
    tb.base[6] = d_in[13]; tb.off[6] = 0;         tb.dst[6] = Wt3;
    trans_kernel<<<dim3(16, 7), 256, 0, stream>>>(tb, flag);

    // ---- CSR build (4 keys: er_src, er_dst, ee_src, rr_src) ----
    zero_kernel<<<(4 * N + 255) / 256, 256, 0, stream>>>(degcur, 4 * N);
    int Emax = Eer > Eee ? Eer : Eee;
    if (Err > Emax) Emax = Err;
    count4_kernel<<<dim3((Emax + 255) / 256, 4), 256, 0, stream>>>(
        er_src, er_dst, ee_src, rr_src, Eer, Eer, Eee, Err, degcur, N);
    scan_partial_kernel<<<T, 256, 0, stream>>>(degcur, tsum, N, ntpa);
    scan_tiles_kernel<<<1, 256, 0, stream>>>(tsum, toff, indptr, N, ntpa);
    scan_final_kernel<<<T, 256, 0, stream>>>(degcur, toff, indptr, N, ntpa);
    scatter_attn2_kernel<<<dim3((Eer + 255) / 256, 2), 256, 0, stream>>>(
        er_src, er_dst, Eer, degcur, N, koth_e, koth_r);
    int Emm = Eee > Err ? Eee : Err;
    scatter_mean2_kernel<<<dim3((Emm + 255) / 256, 2), 256, 0, stream>>>(
        ee_src, ee_dst, Eee, rr_src, rr_dst, Err, degcur, N, dst_ee, dst_rr);

    int GB = (N + 63) / 64;
    int EB = 2048;  // grid-stride: 8 blocks/CU, 4 edges/wave

    // entity side: pair=[r,h]@Wae; key=src(h part,+bae), oth=dst(r part)
    gemm2_mfma_kernel<<<GB, 256, 0, stream>>>(Xc, WtA, bae, part0, part1, N);
    edge_score_kernel<<<EB, 256, 0, stream>>>(part1, part0, koth_e,
                                              w0w, w0b, eij_e, Eer);

    // relation side: pair=[h,r]@War; key=dst(r part,+bar), oth=src(h part)
    gemm2_mfma_kernel<<<GB, 256, 0, stream>>>(Xc, WtR, bar_, part0, part1, N);
    edge_score_kernel<<<EB, 256, 0, stream>>>(part1, part0, koth_r,
                                              w1w, w1b, eij_r, Eer);

    int NG = (N + 15) / 16;  // 16 lanes per node, 16 nodes per block
    node_agg_kernel<<<dim3(NG, 2), 256, 0, stream>>>(
        Xc, eij_e, indptr, koth_e, eij_r, indptr + (N + 1), koth_r,
        indptr + 2 * (N + 1), dst_ee, indptr + 3 * (N + 1), dst_rr,
        attn_agg, mean_agg, N);
    final_mfma_kernel<<<GB, 256, 0, stream>>>(Xc, attn_agg, mean_agg,
                                              Wt1, b1, Wt2, b2, Wt3, b3,
                                              d_out, flag, N);
}